// Round 12
// baseline (387.919 us; speedup 1.0000x reference)
//
#include <hip/hip_runtime.h>
#include <hip/hip_bf16.h>
#include <cstdint>
#include <cstddef>

#define BATCH 2
#define SEQ 2048
#define DMODEL 1024
#define DIN 2048
#define NH 32
#define HEADDIM 64
#define DSTATE 64
#define DCONV 4
#define CONV_DIM (DIN + 2 * DSTATE)          // 2176
#define DPROJ (2 * DIN + 2 * DSTATE + NH)    // 4256
#define MLP_INNER 4096
#define TOKENS (BATCH * SEQ)                 // 4096
#define EPS 1e-5f
#define Q 64
#define NCHUNK (SEQ / Q)                     // 32
#define NCH (BATCH * NCHUNK * NH)            // 2048 chunk-heads
#define LSTR 72                               // 144B rows (16B-aligned)
#define BSTR 68                               // f32 bounce stride (16B-aligned, 2-way banks)
#define NPAD_IN 4352                          // DPROJ padded to 34*128

typedef __attribute__((ext_vector_type(8))) short short8;
typedef __attribute__((ext_vector_type(8))) __bf16 bf16x8;
typedef __attribute__((ext_vector_type(4))) float f32x4;

__device__ inline short f2bf(float f) {
    unsigned u = __builtin_bit_cast(unsigned, f);
    u = (u + 0x7FFFu + ((u >> 16) & 1u)) >> 16;
    return (short)u;
}
__device__ inline float bf2f(short s) {
    unsigned u = ((unsigned)(unsigned short)s) << 16;
    return __builtin_bit_cast(float, u);
}
__device__ inline float silu_f(float x) { return x / (1.f + __expf(-x)); }

__device__ inline bf16x8 ld_frag(const short* p) {
    short8 s = *(const short8*)p;
    return __builtin_bit_cast(bf16x8, s);
}

__device__ inline void glds16(const short* g, short* l) {
    __builtin_amdgcn_global_load_lds(
        (const __attribute__((address_space(1))) void*)g,
        (__attribute__((address_space(3))) void*)l, 16, 0, 0);
}

// ---------------- 128x128-tile bf16 GEMM, KT=64, 8 waves (K=1024 GEMMs) ----
// R10 verdict: 2-barrier structure plateaus at ~26-29% MfmaUtil regardless of
// tile/KT/waves (R6/R8/R10 triangulation) -- frozen. MODE 1/4 as before.
template <int MODE>
__global__ __launch_bounds__(512, 4) void gemm_bf16_kernel(
    const short* __restrict__ A, const short* __restrict__ BT,
    void* __restrict__ Cout, const float* __restrict__ bias,
    int M, int N, int K)
{
    constexpr int KT = 64;
    const int tid  = threadIdx.x;
    const int wid  = tid >> 6;
    const int lane = tid & 63;
    const int lm   = lane & 15;
    const int lg   = lane >> 4;
    const int wm   = (wid >> 2) * 64;
    const int wn   = (wid & 3) * 32;

    const int nb  = gridDim.x * gridDim.y;
    const int bid = blockIdx.y * gridDim.x + blockIdx.x;
    const int per = nb >> 3;
    const int nid = (bid & 7) * per + (bid >> 3);
    const int m0  = (nid / gridDim.x) * 128;
    const int n0  = (nid % gridDim.x) * 128;

    __shared__ __attribute__((aligned(16))) short Al0[128 * KT];
    __shared__ __attribute__((aligned(16))) short Al1[128 * KT];
    __shared__ __attribute__((aligned(16))) short Bl0[128 * KT];
    __shared__ __attribute__((aligned(16))) short Bl1[128 * KT];

    f32x4 acc[4][2];
#pragma unroll
    for (int i = 0; i < 4; ++i)
#pragma unroll
        for (int j = 0; j < 2; ++j) acc[i][j] = {0.f, 0.f, 0.f, 0.f};

    const int srow = lane >> 3;                 // 0..7
    const int scb  = (lane & 7) ^ srow;         // 8-slot XOR via source
    const short* Ag = A  + (size_t)(m0 + wid * 16 + srow) * K + scb * 8;
    const short* Bg = BT + (size_t)(n0 + wid * 16 + srow) * K + scb * 8;
    const int woff = wid * 16 * KT;

    const int niter = K / KT;
    {
#pragma unroll
        for (int j = 0; j < 2; ++j) {
            glds16(Ag + (size_t)j * 8 * K, Al0 + woff + j * 512);
            glds16(Bg + (size_t)j * 8 * K, Bl0 + woff + j * 512);
        }
    }

    for (int i = 0; i < niter; ++i) {
        __syncthreads();
        const short* Ac = (i & 1) ? Al1 : Al0;
        const short* Bc = (i & 1) ? Bl1 : Bl0;
        if (i + 1 < niter) {
            int kt = (i + 1) * KT;
            short* al = ((i & 1) ? Al0 : Al1) + woff;
            short* bl = ((i & 1) ? Bl0 : Bl1) + woff;
#pragma unroll
            for (int j = 0; j < 2; ++j) {
                glds16(Ag + kt + (size_t)j * 8 * K, al + j * 512);
                glds16(Bg + kt + (size_t)j * 8 * K, bl + j * 512);
            }
        }

#pragma unroll
        for (int sub = 0; sub < 2; ++sub) {
            const int cb = sub * 4 + lg;
            bf16x8 af[4], bf[2];
#pragma unroll
            for (int ii = 0; ii < 4; ++ii) {
                int ar = wm + ii * 16 + lm;
                af[ii] = ld_frag(&Ac[ar * KT + ((cb ^ (ar & 7)) * 8)]);
            }
#pragma unroll
            for (int j = 0; j < 2; ++j) {
                int br = wn + j * 16 + lm;
                bf[j] = ld_frag(&Bc[br * KT + ((cb ^ (br & 7)) * 8)]);
            }
#pragma unroll
            for (int ii = 0; ii < 4; ++ii)
#pragma unroll
                for (int j = 0; j < 2; ++j)
                    acc[ii][j] = __builtin_amdgcn_mfma_f32_16x16x32_bf16(af[ii], bf[j], acc[ii][j], 0, 0, 0);
        }
    }

#pragma unroll
    for (int j = 0; j < 2; ++j) {
        int col = n0 + wn + j * 16 + lm;
        if (col >= N) continue;
        float bv = (MODE == 1) ? bias[col] : 0.f;
#pragma unroll
        for (int i = 0; i < 4; ++i) {
#pragma unroll
            for (int r = 0; r < 4; ++r) {
                int row = m0 + wm + i * 16 + lg * 4 + r;
                float v = acc[i][j][r];
                if (MODE == 1) v = silu_f(v + bv);
                ((short*)Cout)[(size_t)row * N + col] = f2bf(v);
            }
        }
    }
}

// ---------------- 64x128-tile bf16 GEMM, KT=64, 8 waves (N=1024 GEMMs) -----
// MODE 2: f32 C=AB+bias+res ; MODE 3: f32 C=AB+res.
template <int MODE>
__global__ __launch_bounds__(512, 4) void gemm64_kernel(
    const short* __restrict__ A, const short* __restrict__ BT,
    void* __restrict__ Cout, const float* __restrict__ bias,
    const float* __restrict__ res, int M, int N, int K)
{
    constexpr int KT = 64;
    const int tid  = threadIdx.x;
    const int wid  = tid >> 6;
    const int lane = tid & 63;
    const int lm   = lane & 15;
    const int lg   = lane >> 4;
    const int wm   = (wid >> 2) * 32;
    const int wn   = (wid & 3) * 32;

    const int nb  = gridDim.x * gridDim.y;
    const int bid = blockIdx.y * gridDim.x + blockIdx.x;
    const int per = nb >> 3;
    const int nid = (bid & 7) * per + (bid >> 3);
    const int m0  = (nid / gridDim.x) * 64;
    const int n0  = (nid % gridDim.x) * 128;

    __shared__ __attribute__((aligned(16))) short Al0[64 * KT];
    __shared__ __attribute__((aligned(16))) short Al1[64 * KT];
    __shared__ __attribute__((aligned(16))) short Bl0[128 * KT];
    __shared__ __attribute__((aligned(16))) short Bl1[128 * KT];

    f32x4 acc[2][2];
#pragma unroll
    for (int i = 0; i < 2; ++i)
#pragma unroll
        for (int j = 0; j < 2; ++j) acc[i][j] = {0.f, 0.f, 0.f, 0.f};

    const int srow = lane >> 3;
    const int scb  = (lane & 7) ^ srow;
    const short* Bg = BT + (size_t)(n0 + wid * 16 + srow) * K + scb * 8;
    const short* Ag = A  + (size_t)(m0 + (wid & 3) * 16 + srow) * K + scb * 8;
    const int woffB = wid * 16 * KT;
    const int woffA = (wid & 3) * 16 * KT;
    const bool doA = (wid < 4);

    const int niter = K / KT;
    {
#pragma unroll
        for (int j = 0; j < 2; ++j) {
            if (doA) glds16(Ag + (size_t)j * 8 * K, Al0 + woffA + j * 512);
            glds16(Bg + (size_t)j * 8 * K, Bl0 + woffB + j * 512);
        }
    }

    for (int i = 0; i < niter; ++i) {
        __syncthreads();
        const short* Ac = (i & 1) ? Al1 : Al0;
        const short* Bc = (i & 1) ? Bl1 : Bl0;
        if (i + 1 < niter) {
            int kt = (i + 1) * KT;
            short* al = ((i & 1) ? Al0 : Al1) + woffA;
            short* bl = ((i & 1) ? Bl0 : Bl1) + woffB;
#pragma unroll
            for (int j = 0; j < 2; ++j) {
                if (doA) glds16(Ag + kt + (size_t)j * 8 * K, al + j * 512);
                glds16(Bg + kt + (size_t)j * 8 * K, bl + j * 512);
            }
        }

#pragma unroll
        for (int sub = 0; sub < 2; ++sub) {
            const int cb = sub * 4 + lg;
            bf16x8 af[2], bf[2];
#pragma unroll
            for (int ii = 0; ii < 2; ++ii) {
                int ar = wm + ii * 16 + lm;
                af[ii] = ld_frag(&Ac[ar * KT + ((cb ^ (ar & 7)) * 8)]);
            }
#pragma unroll
            for (int j = 0; j < 2; ++j) {
                int br = wn + j * 16 + lm;
                bf[j] = ld_frag(&Bc[br * KT + ((cb ^ (br & 7)) * 8)]);
            }
#pragma unroll
            for (int ii = 0; ii < 2; ++ii)
#pragma unroll
                for (int j = 0; j < 2; ++j)
                    acc[ii][j] = __builtin_amdgcn_mfma_f32_16x16x32_bf16(af[ii], bf[j], acc[ii][j], 0, 0, 0);
        }
    }

#pragma unroll
    for (int j = 0; j < 2; ++j) {
        int col = n0 + wn + j * 16 + lm;
        float bv = (MODE == 2) ? bias[col] : 0.f;
#pragma unroll
        for (int i = 0; i < 2; ++i) {
#pragma unroll
            for (int r = 0; r < 4; ++r) {
                int row = m0 + wm + i * 16 + lg * 4 + r;
                float v = acc[i][j][r] + bv + res[(size_t)row * N + col];
                ((float*)Cout)[(size_t)row * N + col] = v;
            }
        }
    }
}

// ---------------- prep: cvt + WinT only (GEMM1's inputs) -------------------
// WoutT/w1T/w2T transposes moved into chunk_kernel's grid (R12): they are
// not needed until steps 5/7/9 and ride chunk's spare HBM bandwidth.
#define PREP_CVT 4096
#define PREP_T1  (PREP_CVT + 4352)   // W_in (136 x 32) -> 8448 blocks total
__global__ __launch_bounds__(256) void prep_kernel(
    const float* __restrict__ x, short* __restrict__ xbf,
    const float* __restrict__ W_in, short* __restrict__ WinT)
{
    int blk = blockIdx.x;
    if (blk < PREP_CVT) {
        int i = blk * 256 + threadIdx.x;
        f32x4 v = *(const f32x4*)(x + (size_t)i * 4);
        short4 o;
        o.x = f2bf(v.x); o.y = f2bf(v.y); o.z = f2bf(v.z); o.w = f2bf(v.w);
        *(short4*)(xbf + (size_t)i * 4) = o;
        return;
    }
    __shared__ float t[32][33];
    int l = blk - PREP_CVT;
    int bx = l % 136, by = l / 136;
    int col = threadIdx.x & 31, row8 = threadIdx.x >> 5;
    int gn = bx * 32 + col;
#pragma unroll
    for (int r = 0; r < 4; ++r) {
        int gk = by * 32 + row8 + r * 8;
        t[row8 + r * 8][col] = (gn < DPROJ) ? W_in[(size_t)gk * DPROJ + gn] : 0.f;
    }
    __syncthreads();
#pragma unroll
    for (int r = 0; r < 4; ++r) {
        int n = bx * 32 + row8 + r * 8;
        WinT[(size_t)n * DMODEL + by * 32 + col] = f2bf(t[col][row8 + r * 8]);
    }
}

// ---------------- conv (k=4, causal) + bias + silu, WITH fused dt ----------
#define CTOK 8
__global__ __launch_bounds__(256) void conv_kernel(
    const short* __restrict__ zx, const float* __restrict__ cw,
    const float* __restrict__ cb, short* __restrict__ xBCc,
    const float* __restrict__ dt_bias, const float* __restrict__ A_log,
    float* __restrict__ dtb, float* __restrict__ ldab)
{
    int c4 = blockIdx.y * 256 + threadIdx.x;
    int m0 = blockIdx.x * CTOK;
    if (c4 >= CONV_DIM / 4) {
        int i0 = (int)threadIdx.x - 32;      // 0..223 (only y==2, tid>=32 lands here)
#pragma unroll
        for (int k = 0; k < 2; ++k) {
            int i = i0 + k * 224;
            if (i < 256) {
                int hh = i & 31;
                int m = m0 + (i >> 5);
                float v = bf2f(zx[(size_t)m * DPROJ + DIN + CONV_DIM + hh]) + dt_bias[hh];
                float dtv_ = (v > 20.f) ? v : log1pf(__expf(v));
                dtb[(size_t)m0 * NH + i]  = dtv_;
                ldab[(size_t)m0 * NH + i] = -__expf(A_log[hh]) * dtv_;
            }
        }
        return;
    }
    int c  = c4 * 4;
    int l0 = m0 & (SEQ - 1);

    const short* base = zx + (size_t)m0 * DPROJ + DIN + c;
    f32x4 win[CTOK + 3];
#pragma unroll
    for (int j = 0; j < CTOK + 3; ++j) {
        int off = j - 3;
        if (l0 + off >= 0) {
            short4 sv = *(const short4*)(base + (ptrdiff_t)off * DPROJ);
            win[j] = {bf2f(sv.x), bf2f(sv.y), bf2f(sv.z), bf2f(sv.w)};
        } else {
            win[j] = {0.f, 0.f, 0.f, 0.f};
        }
    }
    f32x4 w0 = *(const f32x4*)(cw + (c + 0) * DCONV);
    f32x4 w1 = *(const f32x4*)(cw + (c + 1) * DCONV);
    f32x4 w2 = *(const f32x4*)(cw + (c + 2) * DCONV);
    f32x4 w3 = *(const f32x4*)(cw + (c + 3) * DCONV);
    f32x4 bb = *(const f32x4*)(cb + c);

    short* outp = xBCc + (size_t)m0 * CONV_DIM + c;
#pragma unroll
    for (int t = 0; t < CTOK; ++t) {
        f32x4 a = {bb.x, bb.y, bb.z, bb.w};
#pragma unroll
        for (int j = 0; j < DCONV; ++j) {
            f32x4 v = win[t + j];
            a.x += v.x * w0[j];
            a.y += v.y * w1[j];
            a.z += v.z * w2[j];
            a.w += v.w * w3[j];
        }
        short4 o;
        o.x = f2bf(silu_f(a.x)); o.y = f2bf(silu_f(a.y));
        o.z = f2bf(silu_f(a.z)); o.w = f2bf(silu_f(a.w));
        *(short4*)(outp + (size_t)t * CONV_DIM) = o;
    }
}

// ---------------- P1: intra-chunk SSD + absorbed weight transposes ---------
// Blocks [0, NCH): SSD. Blocks [NCH, NCH+10240): WoutT / w1T / w2T 32x32
// transposes (memory-only; overlap chunk's VALU/LDS-heavy SSD blocks, R12).
__global__ __launch_bounds__(256) void chunk_kernel(
    const short* __restrict__ xBCc, const float* __restrict__ dtb,
    const float* __restrict__ ldab, short* __restrict__ ybuf,
    short* __restrict__ Sbuf, float* __restrict__ cumdecay,
    const float* __restrict__ Wo, short* __restrict__ WoT,
    const float* __restrict__ w1, short* __restrict__ w1T,
    const float* __restrict__ w2, short* __restrict__ w2T)
{
    int bid = blockIdx.x;
    int tid = threadIdx.x;

    __shared__ __attribute__((aligned(16))) short Cc[64 * LSTR];
    __shared__ __attribute__((aligned(16))) short Bb[64 * LSTR];
    __shared__ __attribute__((aligned(16))) short BwT[64 * LSTR];
    __shared__ __attribute__((aligned(16))) short Xt[64 * LSTR];
    __shared__ __attribute__((aligned(16))) short Mm[64 * LSTR];
    __shared__ float Lc[64], dtv[64];

    if (bid >= NCH) {
        // ---- absorbed transpose blocks ----
        int l = bid - NCH;
        const float* src; short* dst; int K, N, bx, by;
        if (l < 2048)      {           bx = l % 32;  by = l / 32;  src = Wo; dst = WoT; K = DIN;       N = DMODEL; }
        else if (l < 6144) { l -= 2048; bx = l % 128; by = l / 128; src = w1; dst = w1T; K = DMODEL;    N = MLP_INNER; }
        else               { l -= 6144; bx = l % 32;  by = l / 32;  src = w2; dst = w2T; K = MLP_INNER; N = DMODEL; }
        float (*t)[33] = (float(*)[33])Cc;   // 4.2KB, fits in Cc (9.2KB)
        int col = tid & 31, row8 = tid >> 5;
        int gn = bx * 32 + col;
#pragma unroll
        for (int r = 0; r < 4; ++r) {
            int gk = by * 32 + row8 + r * 8;
            t[row8 + r * 8][col] = (gn < N) ? src[(size_t)gk * N + gn] : 0.f;
        }
        __syncthreads();
#pragma unroll
        for (int r = 0; r < 4; ++r) {
            int n = bx * 32 + row8 + r * 8;
            dst[(size_t)n * K + by * 32 + col] = f2bf(t[col][row8 + r * 8]);
        }
        return;
    }

    int h = bid & 31, c = (bid >> 5) & 31, b = bid >> 10;
    int m0 = b * SEQ + c * Q;
    int wid = tid >> 6, lane = tid & 63, lm = lane & 15, lg = lane >> 4;

    if (tid < 64) {
        int s = tid;
        size_t ix = (size_t)(m0 + s) * NH + h;
        float ld = ldab[ix];
        float dt = dtb[ix];
        float v = ld;
#pragma unroll
        for (int off = 1; off < 64; off <<= 1) {
            float o = __shfl_up(v, off);
            if (s >= off) v += o;
        }
        Lc[s] = v;
        dtv[s] = dt;
        cumdecay[(size_t)bid * 64 + s] = __expf(v);
    }
    {
        int row = tid >> 2, c0 = (tid & 3) * 16;
        const short* pB = xBCc + (size_t)(m0 + row) * CONV_DIM + DIN;
#pragma unroll
        for (int u = 0; u < 2; ++u) {
            short8 vb = *(const short8*)(pB + c0 + 8 * u);
            short8 vc = *(const short8*)(pB + DSTATE + c0 + 8 * u);
            *(short8*)&Bb[row * LSTR + c0 + 8 * u] = vb;
            *(short8*)&Cc[row * LSTR + c0 + 8 * u] = vc;
        }
    }
    __syncthreads();
    {
        int s = tid >> 2, c0 = (tid & 3) * 16;
        float w = dtv[s];
        float w2_ = __expf(Lc[63] - Lc[s]);
        const short* pX = xBCc + (size_t)(m0 + s) * CONV_DIM + h * HEADDIM;
#pragma unroll
        for (int u = 0; u < 4; ++u) {
            short4 v = *(const short4*)(pX + c0 + 4 * u);
            Xt[(c0 + 4 * u + 0) * LSTR + s] = f2bf(bf2f(v.x) * w);
            Xt[(c0 + 4 * u + 1) * LSTR + s] = f2bf(bf2f(v.y) * w);
            Xt[(c0 + 4 * u + 2) * LSTR + s] = f2bf(bf2f(v.z) * w);
            Xt[(c0 + 4 * u + 3) * LSTR + s] = f2bf(bf2f(v.w) * w);
            short4 sb = *(short4*)&Bb[s * LSTR + c0 + 4 * u];
            BwT[(c0 + 4 * u + 0) * LSTR + s] = f2bf(bf2f(sb.x) * w2_);
            BwT[(c0 + 4 * u + 1) * LSTR + s] = f2bf(bf2f(sb.y) * w2_);
            BwT[(c0 + 4 * u + 2) * LSTR + s] = f2bf(bf2f(sb.z) * w2_);
            BwT[(c0 + 4 * u + 3) * LSTR + s] = f2bf(bf2f(sb.w) * w2_);
        }
    }
    __syncthreads();

    {
        bf16x8 af[2];
#pragma unroll
        for (int kk = 0; kk < 2; ++kk)
            af[kk] = ld_frag(&Cc[(wid * 16 + lm) * LSTR + kk * 32 + lg * 8]);
#pragma unroll
        for (int j = 0; j < 4; ++j) {
            f32x4 acc = {0.f, 0.f, 0.f, 0.f};
#pragma unroll
            for (int kk = 0; kk < 2; ++kk) {
                bf16x8 bf = ld_frag(&Bb[(j * 16 + lm) * LSTR + kk * 32 + lg * 8]);
                acc = __builtin_amdgcn_mfma_f32_16x16x32_bf16(af[kk], bf, acc, 0, 0, 0);
            }
            int s = j * 16 + lm;
            float Ls = Lc[s];
#pragma unroll
            for (int r = 0; r < 4; ++r) {
                int t = wid * 16 + lg * 4 + r;
                float val = (s <= t) ? acc[r] * __expf(Lc[t] - Ls) : 0.f;
                Mm[t * LSTR + s] = f2bf(val);
            }
        }
    }
    __syncthreads();

    {
        // Cc/Bb last read in previous phase -> reuse as bounce buffers:
        // Cc <- y tile, Bb <- S tile (bf16, no extra rounding).
        bf16x8 am[2], aw[2];
#pragma unroll
        for (int kk = 0; kk < 2; ++kk) {
            am[kk] = ld_frag(&Mm[(wid * 16 + lm) * LSTR + kk * 32 + lg * 8]);
            aw[kk] = ld_frag(&BwT[(wid * 16 + lm) * LSTR + kk * 32 + lg * 8]);
        }
#pragma unroll
        for (int j = 0; j < 4; ++j) {
            f32x4 a1 = {0.f, 0.f, 0.f, 0.f};
            f32x4 a2 = {0.f, 0.f, 0.f, 0.f};
#pragma unroll
            for (int kk = 0; kk < 2; ++kk) {
                bf16x8 bx = ld_frag(&Xt[(j * 16 + lm) * LSTR + kk * 32 + lg * 8]);
                a1 = __builtin_amdgcn_mfma_f32_16x16x32_bf16(am[kk], bx, a1, 0, 0, 0);
                a2 = __builtin_amdgcn_mfma_f32_16x16x32_bf16(aw[kk], bx, a2, 0, 0, 0);
            }
            int p = j * 16 + lm;
#pragma unroll
            for (int r = 0; r < 4; ++r) {
                int t = wid * 16 + lg * 4 + r;
                Cc[t * LSTR + p] = f2bf(a1[r]);
                Bb[t * LSTR + p] = f2bf(a2[r]);
            }
        }
    }
    __syncthreads();
    {
        // coalesced stores: 4 threads cover one 128B row
        int row = tid >> 2, seg = (tid & 3) * 16;
        short8 y0 = *(short8*)&Cc[row * LSTR + seg];
        short8 y1 = *(short8*)&Cc[row * LSTR + seg + 8];
        short* yb = ybuf + (size_t)(m0 + row) * DIN + h * HEADDIM + seg;
        *(short8*)yb = y0;
        *(short8*)(yb + 8) = y1;
        short8 s0 = *(short8*)&Bb[row * LSTR + seg];
        short8 s1 = *(short8*)&Bb[row * LSTR + seg + 8];
        short* sb = Sbuf + (size_t)bid * 4096 + row * 64 + seg;
        *(short8*)sb = s0;
        *(short8*)(sb + 8) = s1;
    }
}

// ---------------- P2: inter-chunk state recurrence (bf16 S/H in HBM) -------
__global__ __launch_bounds__(256) void state_kernel(
    short* __restrict__ SH, const float* __restrict__ cumdecay)
{
    int bh = blockIdx.x >> 2, st = blockIdx.x & 3;
    int b = bh >> 5, h = bh & 31;
    int off = st * 1024 + threadIdx.x * 4;

    f32x4 H = {0.f, 0.f, 0.f, 0.f};
    int cid = b * NCHUNK * NH + h;
    short4 sv = *(const short4*)(SH + (size_t)cid * 4096 + off);
    float cd_next = cumdecay[(size_t)cid * 64 + 63];

    for (int c = 0; c < NCHUNK; ++c) {
        short4 s4 = sv;
        float cd = cd_next;
        size_t base = (size_t)cid * 4096 + off;
        if (c + 1 < NCHUNK) {
            sv = *(const short4*)(SH + base + (size_t)NH * 4096);
            cd_next = cumdecay[(size_t)(cid + NH) * 64 + 63];
        }
        short4 o;
        o.x = f2bf(H.x); o.y = f2bf(H.y); o.z = f2bf(H.z); o.w = f2bf(H.w);
        *(short4*)(SH + base) = o;
        H.x = cd * H.x + bf2f(s4.x);
        H.y = cd * H.y + bf2f(s4.y);
        H.z = cd * H.z + bf2f(s4.z);
        H.w = cd * H.w + bf2f(s4.w);
        cid += NH;
    }
}

// ---------------- P3: y += exp(Lc_t) * C_t @ H_in; coalesced f32 bounce ----
__global__ __launch_bounds__(256) void inter_kernel(
    const short* __restrict__ xBCc, const short* __restrict__ Hin,
    const float* __restrict__ cumdecay, short* __restrict__ ybuf)
{
    int bid = blockIdx.x;
    int h = bid & 31, c = (bid >> 5) & 31, b = bid >> 10;
    int m0 = b * SEQ + c * Q;
    int tid = threadIdx.x;
    int wid = tid >> 6, lane = tid & 63, lm = lane & 15, lg = lane >> 4;

    __shared__ __attribute__((aligned(16))) short base_lds[2 * 64 * LSTR];
    short* Cc = base_lds;
    short* HT = base_lds + 64 * LSTR;
    __shared__ float eLc[64];

    if (tid < 64) eLc[tid] = cumdecay[(size_t)bid * 64 + tid];
    {
        int row = tid >> 2, c0 = (tid & 3) * 16;
        const short* pC = xBCc + (size_t)(m0 + row) * CONV_DIM + DIN + DSTATE;
#pragma unroll
        for (int u = 0; u < 2; ++u) {
            short8 vc = *(const short8*)(pC + c0 + 8 * u);
            *(short8*)&Cc[row * LSTR + c0 + 8 * u] = vc;
        }
        const short* pH = Hin + (size_t)bid * 4096 + row * 64;
        short8 h0 = *(const short8*)(pH + c0);
        short8 h1 = *(const short8*)(pH + c0 + 8);
#pragma unroll
        for (int u = 0; u < 8; ++u) {
            HT[(c0 + u) * LSTR + row]     = h0[u];
            HT[(c0 + 8 + u) * LSTR + row] = h1[u];
        }
    }
    __syncthreads();

    bf16x8 af[2];
#pragma unroll
    for (int kk = 0; kk < 2; ++kk)
        af[kk] = ld_frag(&Cc[(wid * 16 + lm) * LSTR + kk * 32 + lg * 8]);
    f32x4 accs[4];
#pragma unroll
    for (int j = 0; j < 4; ++j) {
        f32x4 acc = {0.f, 0.f, 0.f, 0.f};
#pragma unroll
        for (int kk = 0; kk < 2; ++kk) {
            bf16x8 bh_ = ld_frag(&HT[(j * 16 + lm) * LSTR + kk * 32 + lg * 8]);
            acc = __builtin_amdgcn_mfma_f32_16x16x32_bf16(af[kk], bh_, acc, 0, 0, 0);
        }
        accs[j] = acc;
    }
    __syncthreads();                 // all Cc/HT reads complete
    {
        float* bnc = (float*)base_lds;   // 64 x BSTR f32
#pragma unroll
        for (int j = 0; j < 4; ++j) {
            int p = j * 16 + lm;
#pragma unroll
            for (int r = 0; r < 4; ++r) {
                int t = wid * 16 + lg * 4 + r;
                bnc[t * BSTR + p] = eLc[t] * accs[j][r];
            }
        }
    }
    __syncthreads();
    {
        float* bnc = (float*)base_lds;
        int row = tid >> 2, seg = (tid & 3) * 16;
        f32x4 b0 = *(f32x4*)&bnc[row * BSTR + seg];
        f32x4 b1 = *(f32x4*)&bnc[row * BSTR + seg + 4];
        f32x4 b2 = *(f32x4*)&bnc[row * BSTR + seg + 8];
        f32x4 b3 = *(f32x4*)&bnc[row * BSTR + seg + 12];
        short* yb = ybuf + (size_t)(m0 + row) * DIN + h * HEADDIM + seg;
        short8 y0 = *(short8*)yb;
        short8 y1 = *(short8*)(yb + 8);
        short8 o0, o1;
#pragma unroll
        for (int u = 0; u < 4; ++u) {
            o0[u]     = f2bf(bf2f(y0[u])     + b0[u]);
            o0[u + 4] = f2bf(bf2f(y0[u + 4]) + b1[u]);
            o1[u]     = f2bf(bf2f(y1[u])     + b2[u]);
            o1[u + 4] = f2bf(bf2f(y1[u + 4]) + b3[u]);
        }
        *(short8*)yb = o0;
        *(short8*)(yb + 8) = o1;
    }
}

// ---------------- ybf = bf16(rmsnorm((y + D*x) * silu(z), norm_w)) ----------
__global__ __launch_bounds__(256) void norm1_kernel(
    const short* __restrict__ zx, const short* __restrict__ xBCc,
    const float* __restrict__ Dp, const short* __restrict__ y,
    short* __restrict__ ybf, const float* __restrict__ w)
{
    int m = blockIdx.x;
    int t = threadIdx.x;
    int i0 = t * 8;
    const short8 zv = *(const short8*)(zx + (size_t)m * DPROJ + i0);
    const short8 xv = *(const short8*)(xBCc + (size_t)m * CONV_DIM + i0);
    const short8 yv = *(const short8*)(y + (size_t)m * DIN + i0);
    float Dv = Dp[i0 >> 6];           // 8 elems span one head (HEADDIM=64)

    float vals[8];
    float ss = 0.f;
#pragma unroll
    for (int j = 0; j < 8; ++j) {
        float v = (bf2f(yv[j]) + Dv * bf2f(xv[j])) * silu_f(bf2f(zv[j]));
        vals[j] = v;
        ss += v * v;
    }
#pragma unroll
    for (int o = 32; o >= 1; o >>= 1) ss += __shfl_xor(ss, o);
    __shared__ float wsum[4];
    if ((t & 63) == 0) wsum[t >> 6] = ss;
    __syncthreads();
    float tot = wsum[0] + wsum[1] + wsum[2] + wsum[3];
    float scale = rsqrtf(tot / (float)DIN + EPS);

    f32x4 w0 = *(const f32x4*)(w + i0);
    f32x4 w1 = *(const f32x4*)(w + i0 + 4);
    short8 ov;
#pragma unroll
    for (int j = 0; j < 8; ++j) {
        float wj = (j < 4) ? w0[j] : w1[j - 4];
        ov[j] = f2bf(vals[j] * scale * wj);
    }
    *(short8*)(ybf + (size_t)m * DIN + i0) = ov;
}

// ---------------- hnbf = bf16(rmsnorm(h, rms_w)) ----------------
__global__ __launch_bounds__(256) void norm2_kernel(
    const float* __restrict__ hb, short* __restrict__ hnbf, const float* __restrict__ w)
{
    int m = blockIdx.x;
    int t = threadIdx.x;
    int i0 = t * 4;
    f32x4 hv = *(const f32x4*)(hb + (size_t)m * DMODEL + i0);
    float ss = hv.x * hv.x + hv.y * hv.y + hv.z * hv.z + hv.w * hv.w;
#pragma unroll
    for (int o = 32; o >= 1; o >>= 1) ss += __shfl_xor(ss, o);
    __shared__ float wsum[4];
    if ((t & 63) == 0) wsum[t >> 6] = ss;
    __syncthreads();
    float tot = wsum[0] + wsum[1] + wsum[2] + wsum[3];
    float scale = rsqrtf(tot / (float)DMODEL + EPS);
    f32x4 wv = *(const f32x4*)(w + i0);
    short4 ov;
    ov.x = f2bf(hv.x * scale * wv.x);
    ov.y = f2bf(hv.y * scale * wv.y);
    ov.z = f2bf(hv.z * scale * wv.z);
    ov.w = f2bf(hv.w * scale * wv.w);
    *(short4*)(hnbf + (size_t)m * DMODEL + i0) = ov;
}

extern "C" void kernel_launch(void* const* d_in, const int* in_sizes, int n_in,
                              void* d_out, int out_size, void* d_ws, size_t ws_size,
                              hipStream_t stream) {
    const float* x       = (const float*)d_in[0];
    const float* W_in    = (const float*)d_in[1];
    const float* conv_w  = (const float*)d_in[2];
    const float* conv_b  = (const float*)d_in[3];
    const float* dt_bias = (const float*)d_in[4];
    const float* A_log   = (const float*)d_in[5];
    const float* D_param = (const float*)d_in[6];
    const float* norm_w  = (const float*)d_in[7];
    const float* W_out   = (const float*)d_in[8];
    const float* rms_w   = (const float*)d_in[9];
    const float* mlp_w1  = (const float*)d_in[10];
    const float* mlp_b1  = (const float*)d_in[11];
    const float* mlp_w2  = (const float*)d_in[12];
    const float* mlp_b2  = (const float*)d_in[13];
    float* out = (float*)d_out;

    // Workspace: slot SIZES unchanged (f32-sized); ybuf/Sbuf(SH) hold bf16
    // in the front half of their slots. Alias lifetimes: xbf dead after
    // GEMM1; midbf written (step 7) after ybuf last read (step 4); hbuf
    // (f32, SH slot) written after inter consumed bf16 H; WoutT/w1T/w2T
    // written during chunk (step 3), consumed at steps 5/7/8.
    float* ws       = (float*)d_ws;
    float* zxf      = ws;                                  // holds bf16 zx
    float* xBCf     = zxf + (size_t)TOKENS * DPROJ;        // holds bf16 xBCc
    float* dtb      = xBCf + (size_t)TOKENS * CONV_DIM;
    float* ldab     = dtb + (size_t)TOKENS * NH;
    float* cumdecay = ldab + (size_t)TOKENS * NH;
    float* ybuf     = cumdecay + (size_t)TOKENS * NH;      // holds bf16 y
    float* SH       = ybuf + (size_t)TOKENS * DIN;         // holds bf16 S/H
    float* bfarea   = SH + (size_t)NCH * 4096;

    short* zxb   = (short*)zxf;
    short* xBCb  = (short*)xBCf;
    short* xbf   = (short*)ybuf;
    short* midbf = (short*)ybuf;
    short* ybufs = (short*)ybuf;
    short* SHs   = (short*)SH;
    float* hbuf  = SH;
    short* hnbf  = (short*)(SH + (size_t)TOKENS * DMODEL);

    short* ybf   = (short*)bfarea;
    short* WinT  = ybf + (size_t)TOKENS * DIN;
    short* WoutT = WinT + (size_t)NPAD_IN * DMODEL;
    short* w1T   = WoutT + (size_t)DMODEL * DIN;
    short* w2T   = w1T + (size_t)MLP_INNER * DMODEL;

    dim3 blk(256);
    dim3 blk2(512);

    // 0. cvt + WinT only (GEMM1 inputs)
    prep_kernel<<<dim3(PREP_T1), blk, 0, stream>>>(x, xbf, W_in, WinT);

    // 1. zx = bf16(x @ W_in)  (128^2 KT=64, 8 waves: 1088 blocks)
    gemm_bf16_kernel<4><<<dim3(NPAD_IN / 128, TOKENS / 128), blk2, 0, stream>>>(
        xbf, WinT, zxb, nullptr, TOKENS, DPROJ, DMODEL);
    // 2. conv + bias + silu + fused dt/ldA
    conv_kernel<<<dim3(TOKENS / CTOK, (CONV_DIM / 4 + 255) / 256), blk, 0, stream>>>(
        zxb, conv_w, conv_b, xBCb, dt_bias, A_log, dtb, ldab);
    // 3. SSD intra-chunk + absorbed WoutT/w1T/w2T transposes (12288 blocks)
    chunk_kernel<<<dim3(NCH + 10240), blk, 0, stream>>>(
        xBCb, dtb, ldab, ybufs, SHs, cumdecay,
        W_out, WoutT, mlp_w1, w1T, mlp_w2, w2T);
    state_kernel<<<dim3(BATCH * NH * 4), blk, 0, stream>>>(SHs, cumdecay);
    inter_kernel<<<dim3(NCH), blk, 0, stream>>>(xBCb, SHs, cumdecay, ybufs);
    // 4. ybf = bf16(rmsnorm((y + D*x) * silu(z)))
    norm1_kernel<<<dim3(TOKENS), blk, 0, stream>>>(zxb, xBCb, D_param, ybufs, ybf, norm_w);
    // 5. h = x + ybf @ W_out  (64x128 KT=64, 8 waves: 512 blocks)
    gemm64_kernel<3><<<dim3(DMODEL / 128, TOKENS / 64), blk2, 0, stream>>>(
        ybf, WoutT, hbuf, nullptr, x, TOKENS, DMODEL, DIN);
    // 6. hnbf = bf16(rmsnorm(h))
    norm2_kernel<<<dim3(TOKENS), blk, 0, stream>>>(hbuf, hnbf, rms_w);
    // 7. midbf = bf16(silu(hnbf @ mlp_w1 + b1))  (128^2 KT=64, 8 waves: 1024 blocks)
    gemm_bf16_kernel<1><<<dim3(MLP_INNER / 128, TOKENS / 128), blk2, 0, stream>>>(
        hnbf, w1T, midbf, mlp_b1, TOKENS, MLP_INNER, DMODEL);
    // 8. out = h + midbf @ mlp_w2 + b2  (64x128 KT=64, 8 waves: 512 blocks)
    gemm64_kernel<2><<<dim3(DMODEL / 128, TOKENS / 64), blk2, 0, stream>>>(
        midbf, w2T, out, mlp_b2, hbuf, TOKENS, DMODEL, MLP_INNER);
}

// Round 14
// 358.586 us; speedup vs baseline: 1.0818x; 1.0818x over previous
//
#include <hip/hip_runtime.h>
#include <hip/hip_bf16.h>
#include <cstdint>
#include <cstddef>

#define BATCH 2
#define SEQ 2048
#define DMODEL 1024
#define DIN 2048
#define NH 32
#define HEADDIM 64
#define DSTATE 64
#define DCONV 4
#define CONV_DIM (DIN + 2 * DSTATE)          // 2176
#define DPROJ (2 * DIN + 2 * DSTATE + NH)    // 4256
#define MLP_INNER 4096
#define TOKENS (BATCH * SEQ)                 // 4096
#define EPS 1e-5f
#define Q 64
#define NCHUNK (SEQ / Q)                     // 32
#define NCH (BATCH * NCHUNK * NH)            // 2048 chunk-heads
#define LSTR 72                               // 144B rows (16B-aligned)
#define BSTR 68                               // f32 bounce stride (16B-aligned, 2-way banks)
#define NPAD_IN 4352                          // DPROJ padded to 34*128

typedef __attribute__((ext_vector_type(8))) short short8;
typedef __attribute__((ext_vector_type(8))) __bf16 bf16x8;
typedef __attribute__((ext_vector_type(4))) float f32x4;

__device__ inline short f2bf(float f) {
    unsigned u = __builtin_bit_cast(unsigned, f);
    u = (u + 0x7FFFu + ((u >> 16) & 1u)) >> 16;
    return (short)u;
}
__device__ inline float bf2f(short s) {
    unsigned u = ((unsigned)(unsigned short)s) << 16;
    return __builtin_bit_cast(float, u);
}
__device__ inline float silu_f(float x) { return x / (1.f + __expf(-x)); }

__device__ inline bf16x8 ld_frag(const short* p) {
    short8 s = *(const short8*)p;
    return __builtin_bit_cast(bf16x8, s);
}

__device__ inline void glds16(const short* g, short* l) {
    __builtin_amdgcn_global_load_lds(
        (const __attribute__((address_space(1))) void*)g,
        (__attribute__((address_space(3))) void*)l, 16, 0, 0);
}

// ---------------- 128x128-tile bf16 GEMM, KT=64, 8 waves (K=1024 GEMMs) ----
// R10 verdict: 2-barrier structure plateaus at ~26-29% MfmaUtil regardless of
// tile/KT/waves (R6/R8/R10 triangulation) -- frozen. MODE 1/4 as before.
// R12 lesson: do NOT absorb foreign light blocks into heavy-LDS kernels
// (static LDS is per-kernel; light blocks inherit the footprint).
template <int MODE>
__global__ __launch_bounds__(512, 4) void gemm_bf16_kernel(
    const short* __restrict__ A, const short* __restrict__ BT,
    void* __restrict__ Cout, const float* __restrict__ bias,
    int M, int N, int K)
{
    constexpr int KT = 64;
    const int tid  = threadIdx.x;
    const int wid  = tid >> 6;
    const int lane = tid & 63;
    const int lm   = lane & 15;
    const int lg   = lane >> 4;
    const int wm   = (wid >> 2) * 64;
    const int wn   = (wid & 3) * 32;

    const int nb  = gridDim.x * gridDim.y;
    const int bid = blockIdx.y * gridDim.x + blockIdx.x;
    const int per = nb >> 3;
    const int nid = (bid & 7) * per + (bid >> 3);
    const int m0  = (nid / gridDim.x) * 128;
    const int n0  = (nid % gridDim.x) * 128;

    __shared__ __attribute__((aligned(16))) short Al0[128 * KT];
    __shared__ __attribute__((aligned(16))) short Al1[128 * KT];
    __shared__ __attribute__((aligned(16))) short Bl0[128 * KT];
    __shared__ __attribute__((aligned(16))) short Bl1[128 * KT];

    f32x4 acc[4][2];
#pragma unroll
    for (int i = 0; i < 4; ++i)
#pragma unroll
        for (int j = 0; j < 2; ++j) acc[i][j] = {0.f, 0.f, 0.f, 0.f};

    const int srow = lane >> 3;                 // 0..7
    const int scb  = (lane & 7) ^ srow;         // 8-slot XOR via source
    const short* Ag = A  + (size_t)(m0 + wid * 16 + srow) * K + scb * 8;
    const short* Bg = BT + (size_t)(n0 + wid * 16 + srow) * K + scb * 8;
    const int woff = wid * 16 * KT;

    const int niter = K / KT;
    {
#pragma unroll
        for (int j = 0; j < 2; ++j) {
            glds16(Ag + (size_t)j * 8 * K, Al0 + woff + j * 512);
            glds16(Bg + (size_t)j * 8 * K, Bl0 + woff + j * 512);
        }
    }

    for (int i = 0; i < niter; ++i) {
        __syncthreads();
        const short* Ac = (i & 1) ? Al1 : Al0;
        const short* Bc = (i & 1) ? Bl1 : Bl0;
        if (i + 1 < niter) {
            int kt = (i + 1) * KT;
            short* al = ((i & 1) ? Al0 : Al1) + woff;
            short* bl = ((i & 1) ? Bl0 : Bl1) + woff;
#pragma unroll
            for (int j = 0; j < 2; ++j) {
                glds16(Ag + kt + (size_t)j * 8 * K, al + j * 512);
                glds16(Bg + kt + (size_t)j * 8 * K, bl + j * 512);
            }
        }

#pragma unroll
        for (int sub = 0; sub < 2; ++sub) {
            const int cb = sub * 4 + lg;
            bf16x8 af[4], bf[2];
#pragma unroll
            for (int ii = 0; ii < 4; ++ii) {
                int ar = wm + ii * 16 + lm;
                af[ii] = ld_frag(&Ac[ar * KT + ((cb ^ (ar & 7)) * 8)]);
            }
#pragma unroll
            for (int j = 0; j < 2; ++j) {
                int br = wn + j * 16 + lm;
                bf[j] = ld_frag(&Bc[br * KT + ((cb ^ (br & 7)) * 8)]);
            }
#pragma unroll
            for (int ii = 0; ii < 4; ++ii)
#pragma unroll
                for (int j = 0; j < 2; ++j)
                    acc[ii][j] = __builtin_amdgcn_mfma_f32_16x16x32_bf16(af[ii], bf[j], acc[ii][j], 0, 0, 0);
        }
    }

#pragma unroll
    for (int j = 0; j < 2; ++j) {
        int col = n0 + wn + j * 16 + lm;
        if (col >= N) continue;
        float bv = (MODE == 1) ? bias[col] : 0.f;
#pragma unroll
        for (int i = 0; i < 4; ++i) {
#pragma unroll
            for (int r = 0; r < 4; ++r) {
                int row = m0 + wm + i * 16 + lg * 4 + r;
                float v = acc[i][j][r];
                if (MODE == 1) v = silu_f(v + bv);
                ((short*)Cout)[(size_t)row * N + col] = f2bf(v);
            }
        }
    }
}

// ---------------- 64x128-tile bf16 GEMM, KT=64, 8 waves (N=1024 GEMMs) -----
// MODE 2: f32 C=AB+bias+res ; MODE 3: f32 C=AB+res.
template <int MODE>
__global__ __launch_bounds__(512, 4) void gemm64_kernel(
    const short* __restrict__ A, const short* __restrict__ BT,
    void* __restrict__ Cout, const float* __restrict__ bias,
    const float* __restrict__ res, int M, int N, int K)
{
    constexpr int KT = 64;
    const int tid  = threadIdx.x;
    const int wid  = tid >> 6;
    const int lane = tid & 63;
    const int lm   = lane & 15;
    const int lg   = lane >> 4;
    const int wm   = (wid >> 2) * 32;
    const int wn   = (wid & 3) * 32;

    const int nb  = gridDim.x * gridDim.y;
    const int bid = blockIdx.y * gridDim.x + blockIdx.x;
    const int per = nb >> 3;
    const int nid = (bid & 7) * per + (bid >> 3);
    const int m0  = (nid / gridDim.x) * 64;
    const int n0  = (nid % gridDim.x) * 128;

    __shared__ __attribute__((aligned(16))) short Al0[64 * KT];
    __shared__ __attribute__((aligned(16))) short Al1[64 * KT];
    __shared__ __attribute__((aligned(16))) short Bl0[128 * KT];
    __shared__ __attribute__((aligned(16))) short Bl1[128 * KT];

    f32x4 acc[2][2];
#pragma unroll
    for (int i = 0; i < 2; ++i)
#pragma unroll
        for (int j = 0; j < 2; ++j) acc[i][j] = {0.f, 0.f, 0.f, 0.f};

    const int srow = lane >> 3;
    const int scb  = (lane & 7) ^ srow;
    const short* Bg = BT + (size_t)(n0 + wid * 16 + srow) * K + scb * 8;
    const short* Ag = A  + (size_t)(m0 + (wid & 3) * 16 + srow) * K + scb * 8;
    const int woffB = wid * 16 * KT;
    const int woffA = (wid & 3) * 16 * KT;
    const bool doA = (wid < 4);

    const int niter = K / KT;
    {
#pragma unroll
        for (int j = 0; j < 2; ++j) {
            if (doA) glds16(Ag + (size_t)j * 8 * K, Al0 + woffA + j * 512);
            glds16(Bg + (size_t)j * 8 * K, Bl0 + woffB + j * 512);
        }
    }

    for (int i = 0; i < niter; ++i) {
        __syncthreads();
        const short* Ac = (i & 1) ? Al1 : Al0;
        const short* Bc = (i & 1) ? Bl1 : Bl0;
        if (i + 1 < niter) {
            int kt = (i + 1) * KT;
            short* al = ((i & 1) ? Al0 : Al1) + woffA;
            short* bl = ((i & 1) ? Bl0 : Bl1) + woffB;
#pragma unroll
            for (int j = 0; j < 2; ++j) {
                if (doA) glds16(Ag + kt + (size_t)j * 8 * K, al + j * 512);
                glds16(Bg + kt + (size_t)j * 8 * K, bl + j * 512);
            }
        }

#pragma unroll
        for (int sub = 0; sub < 2; ++sub) {
            const int cb = sub * 4 + lg;
            bf16x8 af[2], bf[2];
#pragma unroll
            for (int ii = 0; ii < 2; ++ii) {
                int ar = wm + ii * 16 + lm;
                af[ii] = ld_frag(&Ac[ar * KT + ((cb ^ (ar & 7)) * 8)]);
            }
#pragma unroll
            for (int j = 0; j < 2; ++j) {
                int br = wn + j * 16 + lm;
                bf[j] = ld_frag(&Bc[br * KT + ((cb ^ (br & 7)) * 8)]);
            }
#pragma unroll
            for (int ii = 0; ii < 2; ++ii)
#pragma unroll
                for (int j = 0; j < 2; ++j)
                    acc[ii][j] = __builtin_amdgcn_mfma_f32_16x16x32_bf16(af[ii], bf[j], acc[ii][j], 0, 0, 0);
        }
    }

#pragma unroll
    for (int j = 0; j < 2; ++j) {
        int col = n0 + wn + j * 16 + lm;
        float bv = (MODE == 2) ? bias[col] : 0.f;
#pragma unroll
        for (int i = 0; i < 2; ++i) {
#pragma unroll
            for (int r = 0; r < 4; ++r) {
                int row = m0 + wm + i * 16 + lg * 4 + r;
                float v = acc[i][j][r] + bv + res[(size_t)row * N + col];
                ((float*)Cout)[(size_t)row * N + col] = v;
            }
        }
    }
}

// ---------------- prep: cvt + 4 weight transposes in ONE launch ------------
// R11 configuration (best measured). R12's absorb-into-chunk regressed.
#define PREP_CVT 4096
#define PREP_T1  (PREP_CVT + 4352)   // W_in  (136 x 32)
#define PREP_T2  (PREP_T1 + 2048)    // W_out (32 x 64)
#define PREP_T3  (PREP_T2 + 4096)    // w1    (128 x 32)
#define PREP_T4  (PREP_T3 + 4096)    // w2    (32 x 128)  -> 18688 blocks total
__global__ __launch_bounds__(256) void prep_kernel(
    const float* __restrict__ x, short* __restrict__ xbf,
    const float* __restrict__ W_in, short* __restrict__ WinT,
    const float* __restrict__ W_out, short* __restrict__ WoutT,
    const float* __restrict__ w1, short* __restrict__ w1T,
    const float* __restrict__ w2, short* __restrict__ w2T)
{
    int blk = blockIdx.x;
    if (blk < PREP_CVT) {
        int i = blk * 256 + threadIdx.x;
        f32x4 v = *(const f32x4*)(x + (size_t)i * 4);
        short4 o;
        o.x = f2bf(v.x); o.y = f2bf(v.y); o.z = f2bf(v.z); o.w = f2bf(v.w);
        *(short4*)(xbf + (size_t)i * 4) = o;
        return;
    }
    __shared__ float t[32][33];
    const float* src; short* dst; int K, N, bx, by;
    if (blk < PREP_T1)      { int l = blk - PREP_CVT; bx = l % 136; by = l / 136; src = W_in;  dst = WinT;  K = DMODEL;    N = DPROJ; }
    else if (blk < PREP_T2) { int l = blk - PREP_T1;  bx = l % 32;  by = l / 32;  src = W_out; dst = WoutT; K = DIN;       N = DMODEL; }
    else if (blk < PREP_T3) { int l = blk - PREP_T2;  bx = l % 128; by = l / 128; src = w1;    dst = w1T;   K = DMODEL;    N = MLP_INNER; }
    else                    { int l = blk - PREP_T3;  bx = l % 32;  by = l / 32;  src = w2;    dst = w2T;   K = MLP_INNER; N = DMODEL; }

    int col = threadIdx.x & 31, row8 = threadIdx.x >> 5;
    int gn = bx * 32 + col;
#pragma unroll
    for (int r = 0; r < 4; ++r) {
        int gk = by * 32 + row8 + r * 8;
        t[row8 + r * 8][col] = (gn < N) ? src[(size_t)gk * N + gn] : 0.f;
    }
    __syncthreads();
#pragma unroll
    for (int r = 0; r < 4; ++r) {
        int n = bx * 32 + row8 + r * 8;
        dst[(size_t)n * K + by * 32 + col] = f2bf(t[col][row8 + r * 8]);
    }
}

// ---------------- conv (k=4, causal) + bias + silu, WITH fused dt ----------
#define CTOK 8
__global__ __launch_bounds__(256) void conv_kernel(
    const short* __restrict__ zx, const float* __restrict__ cw,
    const float* __restrict__ cb, short* __restrict__ xBCc,
    const float* __restrict__ dt_bias, const float* __restrict__ A_log,
    float* __restrict__ dtb, float* __restrict__ ldab)
{
    int c4 = blockIdx.y * 256 + threadIdx.x;
    int m0 = blockIdx.x * CTOK;
    if (c4 >= CONV_DIM / 4) {
        int i0 = (int)threadIdx.x - 32;      // 0..223 (only y==2, tid>=32 lands here)
#pragma unroll
        for (int k = 0; k < 2; ++k) {
            int i = i0 + k * 224;
            if (i < 256) {
                int hh = i & 31;
                int m = m0 + (i >> 5);
                float v = bf2f(zx[(size_t)m * DPROJ + DIN + CONV_DIM + hh]) + dt_bias[hh];
                float dtv_ = (v > 20.f) ? v : log1pf(__expf(v));
                dtb[(size_t)m0 * NH + i]  = dtv_;
                ldab[(size_t)m0 * NH + i] = -__expf(A_log[hh]) * dtv_;
            }
        }
        return;
    }
    int c  = c4 * 4;
    int l0 = m0 & (SEQ - 1);

    const short* base = zx + (size_t)m0 * DPROJ + DIN + c;
    f32x4 win[CTOK + 3];
#pragma unroll
    for (int j = 0; j < CTOK + 3; ++j) {
        int off = j - 3;
        if (l0 + off >= 0) {
            short4 sv = *(const short4*)(base + (ptrdiff_t)off * DPROJ);
            win[j] = {bf2f(sv.x), bf2f(sv.y), bf2f(sv.z), bf2f(sv.w)};
        } else {
            win[j] = {0.f, 0.f, 0.f, 0.f};
        }
    }
    f32x4 w0 = *(const f32x4*)(cw + (c + 0) * DCONV);
    f32x4 w1 = *(const f32x4*)(cw + (c + 1) * DCONV);
    f32x4 w2 = *(const f32x4*)(cw + (c + 2) * DCONV);
    f32x4 w3 = *(const f32x4*)(cw + (c + 3) * DCONV);
    f32x4 bb = *(const f32x4*)(cb + c);

    short* outp = xBCc + (size_t)m0 * CONV_DIM + c;
#pragma unroll
    for (int t = 0; t < CTOK; ++t) {
        f32x4 a = {bb.x, bb.y, bb.z, bb.w};
#pragma unroll
        for (int j = 0; j < DCONV; ++j) {
            f32x4 v = win[t + j];
            a.x += v.x * w0[j];
            a.y += v.y * w1[j];
            a.z += v.z * w2[j];
            a.w += v.w * w3[j];
        }
        short4 o;
        o.x = f2bf(silu_f(a.x)); o.y = f2bf(silu_f(a.y));
        o.z = f2bf(silu_f(a.z)); o.w = f2bf(silu_f(a.w));
        *(short4*)(outp + (size_t)t * CONV_DIM) = o;
    }
}

// ---------------- P1: intra-chunk SSD; coalesced bounce epilogue -----------
__global__ __launch_bounds__(256) void chunk_kernel(
    const short* __restrict__ xBCc, const float* __restrict__ dtb,
    const float* __restrict__ ldab, short* __restrict__ ybuf,
    short* __restrict__ Sbuf, float* __restrict__ cumdecay)
{
    int bid = blockIdx.x;
    int h = bid & 31, c = (bid >> 5) & 31, b = bid >> 10;
    int m0 = b * SEQ + c * Q;
    int tid = threadIdx.x;
    int wid = tid >> 6, lane = tid & 63, lm = lane & 15, lg = lane >> 4;

    __shared__ __attribute__((aligned(16))) short Cc[64 * LSTR];
    __shared__ __attribute__((aligned(16))) short Bb[64 * LSTR];
    __shared__ __attribute__((aligned(16))) short BwT[64 * LSTR];
    __shared__ __attribute__((aligned(16))) short Xt[64 * LSTR];
    __shared__ __attribute__((aligned(16))) short Mm[64 * LSTR];
    __shared__ float Lc[64], dtv[64];

    if (tid < 64) {
        int s = tid;
        size_t ix = (size_t)(m0 + s) * NH + h;
        float ld = ldab[ix];
        float dt = dtb[ix];
        float v = ld;
#pragma unroll
        for (int off = 1; off < 64; off <<= 1) {
            float o = __shfl_up(v, off);
            if (s >= off) v += o;
        }
        Lc[s] = v;
        dtv[s] = dt;
        cumdecay[(size_t)bid * 64 + s] = __expf(v);
    }
    {
        int row = tid >> 2, c0 = (tid & 3) * 16;
        const short* pB = xBCc + (size_t)(m0 + row) * CONV_DIM + DIN;
#pragma unroll
        for (int u = 0; u < 2; ++u) {
            short8 vb = *(const short8*)(pB + c0 + 8 * u);
            short8 vc = *(const short8*)(pB + DSTATE + c0 + 8 * u);
            *(short8*)&Bb[row * LSTR + c0 + 8 * u] = vb;
            *(short8*)&Cc[row * LSTR + c0 + 8 * u] = vc;
        }
    }
    __syncthreads();
    {
        int s = tid >> 2, c0 = (tid & 3) * 16;
        float w = dtv[s];
        float w2 = __expf(Lc[63] - Lc[s]);
        const short* pX = xBCc + (size_t)(m0 + s) * CONV_DIM + h * HEADDIM;
#pragma unroll
        for (int u = 0; u < 4; ++u) {
            short4 v = *(const short4*)(pX + c0 + 4 * u);
            Xt[(c0 + 4 * u + 0) * LSTR + s] = f2bf(bf2f(v.x) * w);
            Xt[(c0 + 4 * u + 1) * LSTR + s] = f2bf(bf2f(v.y) * w);
            Xt[(c0 + 4 * u + 2) * LSTR + s] = f2bf(bf2f(v.z) * w);
            Xt[(c0 + 4 * u + 3) * LSTR + s] = f2bf(bf2f(v.w) * w);
            short4 sb = *(short4*)&Bb[s * LSTR + c0 + 4 * u];
            BwT[(c0 + 4 * u + 0) * LSTR + s] = f2bf(bf2f(sb.x) * w2);
            BwT[(c0 + 4 * u + 1) * LSTR + s] = f2bf(bf2f(sb.y) * w2);
            BwT[(c0 + 4 * u + 2) * LSTR + s] = f2bf(bf2f(sb.z) * w2);
            BwT[(c0 + 4 * u + 3) * LSTR + s] = f2bf(bf2f(sb.w) * w2);
        }
    }
    __syncthreads();

    {
        bf16x8 af[2];
#pragma unroll
        for (int kk = 0; kk < 2; ++kk)
            af[kk] = ld_frag(&Cc[(wid * 16 + lm) * LSTR + kk * 32 + lg * 8]);
#pragma unroll
        for (int j = 0; j < 4; ++j) {
            f32x4 acc = {0.f, 0.f, 0.f, 0.f};
#pragma unroll
            for (int kk = 0; kk < 2; ++kk) {
                bf16x8 bf = ld_frag(&Bb[(j * 16 + lm) * LSTR + kk * 32 + lg * 8]);
                acc = __builtin_amdgcn_mfma_f32_16x16x32_bf16(af[kk], bf, acc, 0, 0, 0);
            }
            int s = j * 16 + lm;
            float Ls = Lc[s];
#pragma unroll
            for (int r = 0; r < 4; ++r) {
                int t = wid * 16 + lg * 4 + r;
                float val = (s <= t) ? acc[r] * __expf(Lc[t] - Ls) : 0.f;
                Mm[t * LSTR + s] = f2bf(val);
            }
        }
    }
    __syncthreads();

    {
        // Cc/Bb last read in previous phase (barrier above) -> reuse as
        // bounce buffers: Cc <- y tile, Bb <- S tile (bf16, no extra rounding).
        bf16x8 am[2], aw[2];
#pragma unroll
        for (int kk = 0; kk < 2; ++kk) {
            am[kk] = ld_frag(&Mm[(wid * 16 + lm) * LSTR + kk * 32 + lg * 8]);
            aw[kk] = ld_frag(&BwT[(wid * 16 + lm) * LSTR + kk * 32 + lg * 8]);
        }
#pragma unroll
        for (int j = 0; j < 4; ++j) {
            f32x4 a1 = {0.f, 0.f, 0.f, 0.f};
            f32x4 a2 = {0.f, 0.f, 0.f, 0.f};
#pragma unroll
            for (int kk = 0; kk < 2; ++kk) {
                bf16x8 bx = ld_frag(&Xt[(j * 16 + lm) * LSTR + kk * 32 + lg * 8]);
                a1 = __builtin_amdgcn_mfma_f32_16x16x32_bf16(am[kk], bx, a1, 0, 0, 0);
                a2 = __builtin_amdgcn_mfma_f32_16x16x32_bf16(aw[kk], bx, a2, 0, 0, 0);
            }
            int p = j * 16 + lm;
#pragma unroll
            for (int r = 0; r < 4; ++r) {
                int t = wid * 16 + lg * 4 + r;
                Cc[t * LSTR + p] = f2bf(a1[r]);
                Bb[t * LSTR + p] = f2bf(a2[r]);
            }
        }
    }
    __syncthreads();
    {
        // coalesced stores: 4 threads cover one 128B row
        int row = tid >> 2, seg = (tid & 3) * 16;
        short8 y0 = *(short8*)&Cc[row * LSTR + seg];
        short8 y1 = *(short8*)&Cc[row * LSTR + seg + 8];
        short* yb = ybuf + (size_t)(m0 + row) * DIN + h * HEADDIM + seg;
        *(short8*)yb = y0;
        *(short8*)(yb + 8) = y1;
        short8 s0 = *(short8*)&Bb[row * LSTR + seg];
        short8 s1 = *(short8*)&Bb[row * LSTR + seg + 8];
        short* sb = Sbuf + (size_t)bid * 4096 + row * 64 + seg;
        *(short8*)sb = s0;
        *(short8*)(sb + 8) = s1;
    }
}

// ---------------- P2: inter-chunk state recurrence (bf16 S/H in HBM) -------
__global__ __launch_bounds__(256) void state_kernel(
    short* __restrict__ SH, const float* __restrict__ cumdecay)
{
    int bh = blockIdx.x >> 2, st = blockIdx.x & 3;
    int b = bh >> 5, h = bh & 31;
    int off = st * 1024 + threadIdx.x * 4;

    f32x4 H = {0.f, 0.f, 0.f, 0.f};
    int cid = b * NCHUNK * NH + h;
    short4 sv = *(const short4*)(SH + (size_t)cid * 4096 + off);
    float cd_next = cumdecay[(size_t)cid * 64 + 63];

    for (int c = 0; c < NCHUNK; ++c) {
        short4 s4 = sv;
        float cd = cd_next;
        size_t base = (size_t)cid * 4096 + off;
        if (c + 1 < NCHUNK) {
            sv = *(const short4*)(SH + base + (size_t)NH * 4096);
            cd_next = cumdecay[(size_t)(cid + NH) * 64 + 63];
        }
        short4 o;
        o.x = f2bf(H.x); o.y = f2bf(H.y); o.z = f2bf(H.z); o.w = f2bf(H.w);
        *(short4*)(SH + base) = o;
        H.x = cd * H.x + bf2f(s4.x);
        H.y = cd * H.y + bf2f(s4.y);
        H.z = cd * H.z + bf2f(s4.z);
        H.w = cd * H.w + bf2f(s4.w);
        cid += NH;
    }
}

// ---------------- P3: y += exp(Lc_t) * C_t @ H_in; coalesced f32 bounce ----
__global__ __launch_bounds__(256) void inter_kernel(
    const short* __restrict__ xBCc, const short* __restrict__ Hin,
    const float* __restrict__ cumdecay, short* __restrict__ ybuf)
{
    int bid = blockIdx.x;
    int h = bid & 31, c = (bid >> 5) & 31, b = bid >> 10;
    int m0 = b * SEQ + c * Q;
    int tid = threadIdx.x;
    int wid = tid >> 6, lane = tid & 63, lm = lane & 15, lg = lane >> 4;

    __shared__ __attribute__((aligned(16))) short base_lds[2 * 64 * LSTR];
    short* Cc = base_lds;
    short* HT = base_lds + 64 * LSTR;
    __shared__ float eLc[64];

    if (tid < 64) eLc[tid] = cumdecay[(size_t)bid * 64 + tid];
    {
        int row = tid >> 2, c0 = (tid & 3) * 16;
        const short* pC = xBCc + (size_t)(m0 + row) * CONV_DIM + DIN + DSTATE;
#pragma unroll
        for (int u = 0; u < 2; ++u) {
            short8 vc = *(const short8*)(pC + c0 + 8 * u);
            *(short8*)&Cc[row * LSTR + c0 + 8 * u] = vc;
        }
        const short* pH = Hin + (size_t)bid * 4096 + row * 64;
        short8 h0 = *(const short8*)(pH + c0);
        short8 h1 = *(const short8*)(pH + c0 + 8);
#pragma unroll
        for (int u = 0; u < 8; ++u) {
            HT[(c0 + u) * LSTR + row]     = h0[u];
            HT[(c0 + 8 + u) * LSTR + row] = h1[u];
        }
    }
    __syncthreads();

    bf16x8 af[2];
#pragma unroll
    for (int kk = 0; kk < 2; ++kk)
        af[kk] = ld_frag(&Cc[(wid * 16 + lm) * LSTR + kk * 32 + lg * 8]);
    f32x4 accs[4];
#pragma unroll
    for (int j = 0; j < 4; ++j) {
        f32x4 acc = {0.f, 0.f, 0.f, 0.f};
#pragma unroll
        for (int kk = 0; kk < 2; ++kk) {
            bf16x8 bh_ = ld_frag(&HT[(j * 16 + lm) * LSTR + kk * 32 + lg * 8]);
            acc = __builtin_amdgcn_mfma_f32_16x16x32_bf16(af[kk], bh_, acc, 0, 0, 0);
        }
        accs[j] = acc;
    }
    __syncthreads();                 // all Cc/HT reads complete
    {
        float* bnc = (float*)base_lds;   // 64 x BSTR f32
#pragma unroll
        for (int j = 0; j < 4; ++j) {
            int p = j * 16 + lm;
#pragma unroll
            for (int r = 0; r < 4; ++r) {
                int t = wid * 16 + lg * 4 + r;
                bnc[t * BSTR + p] = eLc[t] * accs[j][r];
            }
        }
    }
    __syncthreads();
    {
        float* bnc = (float*)base_lds;
        int row = tid >> 2, seg = (tid & 3) * 16;
        f32x4 b0 = *(f32x4*)&bnc[row * BSTR + seg];
        f32x4 b1 = *(f32x4*)&bnc[row * BSTR + seg + 4];
        f32x4 b2 = *(f32x4*)&bnc[row * BSTR + seg + 8];
        f32x4 b3 = *(f32x4*)&bnc[row * BSTR + seg + 12];
        short* yb = ybuf + (size_t)(m0 + row) * DIN + h * HEADDIM + seg;
        short8 y0 = *(short8*)yb;
        short8 y1 = *(short8*)(yb + 8);
        short8 o0, o1;
#pragma unroll
        for (int u = 0; u < 4; ++u) {
            o0[u]     = f2bf(bf2f(y0[u])     + b0[u]);
            o0[u + 4] = f2bf(bf2f(y0[u + 4]) + b1[u]);
            o1[u]     = f2bf(bf2f(y1[u])     + b2[u]);
            o1[u + 4] = f2bf(bf2f(y1[u + 4]) + b3[u]);
        }
        *(short8*)yb = o0;
        *(short8*)(yb + 8) = o1;
    }
}

// ---------------- ybf = bf16(rmsnorm((y + D*x) * silu(z), norm_w)) ----------
__global__ __launch_bounds__(256) void norm1_kernel(
    const short* __restrict__ zx, const short* __restrict__ xBCc,
    const float* __restrict__ Dp, const short* __restrict__ y,
    short* __restrict__ ybf, const float* __restrict__ w)
{
    int m = blockIdx.x;
    int t = threadIdx.x;
    int i0 = t * 8;
    const short8 zv = *(const short8*)(zx + (size_t)m * DPROJ + i0);
    const short8 xv = *(const short8*)(xBCc + (size_t)m * CONV_DIM + i0);
    const short8 yv = *(const short8*)(y + (size_t)m * DIN + i0);
    float Dv = Dp[i0 >> 6];           // 8 elems span one head (HEADDIM=64)

    float vals[8];
    float ss = 0.f;
#pragma unroll
    for (int j = 0; j < 8; ++j) {
        float v = (bf2f(yv[j]) + Dv * bf2f(xv[j])) * silu_f(bf2f(zv[j]));
        vals[j] = v;
        ss += v * v;
    }
#pragma unroll
    for (int o = 32; o >= 1; o >>= 1) ss += __shfl_xor(ss, o);
    __shared__ float wsum[4];
    if ((t & 63) == 0) wsum[t >> 6] = ss;
    __syncthreads();
    float tot = wsum[0] + wsum[1] + wsum[2] + wsum[3];
    float scale = rsqrtf(tot / (float)DIN + EPS);

    f32x4 w0 = *(const f32x4*)(w + i0);
    f32x4 w1 = *(const f32x4*)(w + i0 + 4);
    short8 ov;
#pragma unroll
    for (int j = 0; j < 8; ++j) {
        float wj = (j < 4) ? w0[j] : w1[j - 4];
        ov[j] = f2bf(vals[j] * scale * wj);
    }
    *(short8*)(ybf + (size_t)m * DIN + i0) = ov;
}

// ---------------- hnbf = bf16(rmsnorm(h, rms_w)) ----------------
__global__ __launch_bounds__(256) void norm2_kernel(
    const float* __restrict__ hb, short* __restrict__ hnbf, const float* __restrict__ w)
{
    int m = blockIdx.x;
    int t = threadIdx.x;
    int i0 = t * 4;
    f32x4 hv = *(const f32x4*)(hb + (size_t)m * DMODEL + i0);
    float ss = hv.x * hv.x + hv.y * hv.y + hv.z * hv.z + hv.w * hv.w;
#pragma unroll
    for (int o = 32; o >= 1; o >>= 1) ss += __shfl_xor(ss, o);
    __shared__ float wsum[4];
    if ((t & 63) == 0) wsum[t >> 6] = ss;
    __syncthreads();
    float tot = wsum[0] + wsum[1] + wsum[2] + wsum[3];
    float scale = rsqrtf(tot / (float)DMODEL + EPS);
    f32x4 wv = *(const f32x4*)(w + i0);
    short4 ov;
    ov.x = f2bf(hv.x * scale * wv.x);
    ov.y = f2bf(hv.y * scale * wv.y);
    ov.z = f2bf(hv.z * scale * wv.z);
    ov.w = f2bf(hv.w * scale * wv.w);
    *(short4*)(hnbf + (size_t)m * DMODEL + i0) = ov;
}

extern "C" void kernel_launch(void* const* d_in, const int* in_sizes, int n_in,
                              void* d_out, int out_size, void* d_ws, size_t ws_size,
                              hipStream_t stream) {
    const float* x       = (const float*)d_in[0];
    const float* W_in    = (const float*)d_in[1];
    const float* conv_w  = (const float*)d_in[2];
    const float* conv_b  = (const float*)d_in[3];
    const float* dt_bias = (const float*)d_in[4];
    const float* A_log   = (const float*)d_in[5];
    const float* D_param = (const float*)d_in[6];
    const float* norm_w  = (const float*)d_in[7];
    const float* W_out   = (const float*)d_in[8];
    const float* rms_w   = (const float*)d_in[9];
    const float* mlp_w1  = (const float*)d_in[10];
    const float* mlp_b1  = (const float*)d_in[11];
    const float* mlp_w2  = (const float*)d_in[12];
    const float* mlp_b2  = (const float*)d_in[13];
    float* out = (float*)d_out;

    // Workspace: slot SIZES unchanged (f32-sized); ybuf/Sbuf(SH) hold bf16
    // in the front half of their slots. Alias lifetimes: xbf dead after
    // GEMM1; midbf written (step 7) after ybuf last read (step 4); hbuf
    // (f32, SH slot) written after inter consumed bf16 H.
    float* ws       = (float*)d_ws;
    float* zxf      = ws;                                  // holds bf16 zx
    float* xBCf     = zxf + (size_t)TOKENS * DPROJ;        // holds bf16 xBCc
    float* dtb      = xBCf + (size_t)TOKENS * CONV_DIM;
    float* ldab     = dtb + (size_t)TOKENS * NH;
    float* cumdecay = ldab + (size_t)TOKENS * NH;
    float* ybuf     = cumdecay + (size_t)TOKENS * NH;      // holds bf16 y
    float* SH       = ybuf + (size_t)TOKENS * DIN;         // holds bf16 S/H
    float* bfarea   = SH + (size_t)NCH * 4096;

    short* zxb   = (short*)zxf;
    short* xBCb  = (short*)xBCf;
    short* xbf   = (short*)ybuf;
    short* midbf = (short*)ybuf;
    short* ybufs = (short*)ybuf;
    short* SHs   = (short*)SH;
    float* hbuf  = SH;
    short* hnbf  = (short*)(SH + (size_t)TOKENS * DMODEL);

    short* ybf   = (short*)bfarea;
    short* WinT  = ybf + (size_t)TOKENS * DIN;
    short* WoutT = WinT + (size_t)NPAD_IN * DMODEL;
    short* w1T   = WoutT + (size_t)DMODEL * DIN;
    short* w2T   = w1T + (size_t)MLP_INNER * DMODEL;

    dim3 blk(256);
    dim3 blk2(512);

    // 0. fused conversions / weight transposes (1 launch)
    prep_kernel<<<dim3(PREP_T4), blk, 0, stream>>>(
        x, xbf, W_in, WinT, W_out, WoutT, mlp_w1, w1T, mlp_w2, w2T);

    // 1. zx = bf16(x @ W_in)  (128^2 KT=64, 8 waves: 1088 blocks)
    gemm_bf16_kernel<4><<<dim3(NPAD_IN / 128, TOKENS / 128), blk2, 0, stream>>>(
        xbf, WinT, zxb, nullptr, TOKENS, DPROJ, DMODEL);
    // 2. conv + bias + silu + fused dt/ldA
    conv_kernel<<<dim3(TOKENS / CTOK, (CONV_DIM / 4 + 255) / 256), blk, 0, stream>>>(
        zxb, conv_w, conv_b, xBCb, dt_bias, A_log, dtb, ldab);
    // 3. SSD (bf16 y / S / H intermediates; coalesced epilogues)
    chunk_kernel<<<dim3(NCH), blk, 0, stream>>>(xBCb, dtb, ldab, ybufs, SHs, cumdecay);
    state_kernel<<<dim3(BATCH * NH * 4), blk, 0, stream>>>(SHs, cumdecay);
    inter_kernel<<<dim3(NCH), blk, 0, stream>>>(xBCb, SHs, cumdecay, ybufs);
    // 4. ybf = bf16(rmsnorm((y + D*x) * silu(z)))
    norm1_kernel<<<dim3(TOKENS), blk, 0, stream>>>(zxb, xBCb, D_param, ybufs, ybf, norm_w);
    // 5. h = x + ybf @ W_out  (64x128 KT=64, 8 waves: 512 blocks)
    gemm64_kernel<3><<<dim3(DMODEL / 128, TOKENS / 64), blk2, 0, stream>>>(
        ybf, WoutT, hbuf, nullptr, x, TOKENS, DMODEL, DIN);
    // 6. hnbf = bf16(rmsnorm(h))
    norm2_kernel<<<dim3(TOKENS), blk, 0, stream>>>(hbuf, hnbf, rms_w);
    // 7. midbf = bf16(silu(hnbf @ mlp_w1 + b1))  (128^2 KT=64, 8 waves: 1024 blocks)
    gemm_bf16_kernel<1><<<dim3(MLP_INNER / 128, TOKENS / 128), blk2, 0, stream>>>(
        hnbf, w1T, midbf, mlp_b1, TOKENS, MLP_INNER, DMODEL);
    // 8. out = h + midbf @ mlp_w2 + b2  (64x128 KT=64, 8 waves: 512 blocks)
    gemm64_kernel<2><<<dim3(DMODEL / 128, TOKENS / 64), blk2, 0, stream>>>(
        midbf, w2T, out, mlp_b2, hbuf, TOKENS, DMODEL, MLP_INNER);
}